// Round 8
// baseline (234.441 us; speedup 1.0000x reference)
//
#include <hip/hip_runtime.h>
#include <hip/hip_bf16.h>

// B=4, L=2048, D=1024, H=16, HD=64, K=32, MAXLEN=2048
#define LL 2048

typedef __bf16 bf16x8 __attribute__((ext_vector_type(8)));
typedef __bf16 bf16x4 __attribute__((ext_vector_type(4)));
typedef float f32x4 __attribute__((ext_vector_type(4)));

// async global->LDS, 16B per lane; LDS dest = wave-uniform base + lane*16
__device__ inline void gl_lds16(const __bf16* g, __bf16* l) {
    __builtin_amdgcn_global_load_lds((const __attribute__((address_space(1))) void*)g,
                                     (__attribute__((address_space(3))) void*)l, 16, 0, 0);
}

__device__ inline bf16x8 cvt2bf8(float4 a, float4 b) {
    bf16x8 o;
    o[0] = (__bf16)a.x; o[1] = (__bf16)a.y; o[2] = (__bf16)a.z; o[3] = (__bf16)a.w;
    o[4] = (__bf16)b.x; o[5] = (__bf16)b.y; o[6] = (__bf16)b.z; o[7] = (__bf16)b.w;
    return o;
}

// ---------------------------------------------------------------------------
// prep (2048 blocks): [0,512) cast r1->r1b; [512,1024) transpose Wv;
// [1024,1536) transpose Wo; [1536,2048) transpose r2 (per-head 32x2048->2048x32).
// ---------------------------------------------------------------------------
__global__ __launch_bounds__(256) void prep(const float* __restrict__ r1,
                                            const float* __restrict__ Wv,
                                            const float* __restrict__ Wo,
                                            const float* __restrict__ r2,
                                            __bf16* __restrict__ r1b,
                                            __bf16* __restrict__ Wvt,
                                            __bf16* __restrict__ Wot,
                                            __bf16* __restrict__ r2t) {
    __shared__ float Ls[32][65];
    int bid = blockIdx.x;
    const int tid = threadIdx.x;
    if (bid < 512) {
        const int t = bid * 256 + tid;
        const float4* in4 = (const float4*)r1;
        *(bf16x8*)&r1b[(size_t)t * 8] = cvt2bf8(in4[t * 2], in4[t * 2 + 1]);
        return;
    }
    bid -= 512;
    const float* in;
    __bf16* out;
    int R, C, r0, c0;
    if (bid < 512) {
        in = Wv; out = Wvt; R = 1024; C = 1024;
        c0 = (bid & 15) * 64; r0 = (bid >> 4) * 32;
    } else if (bid < 1024) {
        bid -= 512;
        in = Wo; out = Wot; R = 1024; C = 1024;
        c0 = (bid & 15) * 64; r0 = (bid >> 4) * 32;
    } else {
        bid -= 1024;
        const int bz = bid >> 5;
        in = r2 + (size_t)bz * 65536; out = r2t + (size_t)bz * 65536;
        R = 32; C = 2048;
        c0 = (bid & 31) * 64; r0 = 0;
    }
#pragma unroll
    for (int p = 0; p < 2; ++p) {
        int f = tid + 256 * p;
        int row = f >> 4, c4 = (f & 15) << 2;
        float4 v = *(const float4*)&in[(size_t)(r0 + row) * C + c0 + c4];
        Ls[row][c4 + 0] = v.x; Ls[row][c4 + 1] = v.y;
        Ls[row][c4 + 2] = v.z; Ls[row][c4 + 3] = v.w;
    }
    __syncthreads();
    const int orow = tid >> 2, rc = (tid & 3) << 3;
    bf16x8 o;
#pragma unroll
    for (int j = 0; j < 8; ++j) o[j] = (__bf16)Ls[rc + j][orow];
    *(bf16x8*)&out[(size_t)(c0 + orow) * R + r0 + rc] = o;
}

// ---------------------------------------------------------------------------
// Stage-1 GEMM, fp32 A (cast fused): V = inputs_kv @ Wvt^T + bv.
// A staged via fp32 loads + in-reg cvt + ds_write_b128; B via global_load_lds.
// Epilogue scatters V into fragment-major V3:
//   tile(h, nc=n>>6, b) at ((h*32+nc)*4+b)*4096; within tile:
//   (jt=hd>>4, ks=(n>>5)&1)*512 + (hd&15)*32 + ((n>>3)&3)*8 + (n&7)
// ---------------------------------------------------------------------------
__global__ __launch_bounds__(256) void gemm_af32(const float* __restrict__ A,
                                                 const __bf16* __restrict__ Bt,
                                                 const float* __restrict__ bias,
                                                 __bf16* __restrict__ V3,
                                                 int M, int N, int K) {
    __shared__ alignas(16) __bf16 As[128 * 32];
    __shared__ alignas(16) __bf16 Bs[128 * 32];
    const int tid = threadIdx.x;
    const int lane = tid & 63;
    const int wid = __builtin_amdgcn_readfirstlane(tid >> 6);
    const int row0 = blockIdx.y * 128, col0 = blockIdx.x * 128;
    const int l15 = lane & 15, quad = lane >> 4;
    const int wr = wid & 1, wc = wid >> 1;
    const int s0 = wid * 2, s1 = s0 + 1;

    const int arow = s0 * 16 + (lane >> 2);          // 0..127
    const int k8 = (lane & 3) << 3;
    const float* gaf0 = A + (size_t)(row0 + arow) * K + k8;
    const float* gaf1 = gaf0 + (size_t)16 * K;
    __bf16* lwa0 = As + arow * 32 + k8;
    __bf16* lwa1 = lwa0 + 16 * 32;

    const __bf16* gb0 = Bt + (size_t)(col0 + s0 * 16 + (lane >> 2)) * K + k8;
    const __bf16* gb1 = gb0 + (size_t)16 * K;
    __bf16* lb0 = Bs + s0 * 512;
    __bf16* lb1 = Bs + s1 * 512;

    f32x4 acc[4][4];
#pragma unroll
    for (int i = 0; i < 4; ++i)
#pragma unroll
        for (int j = 0; j < 4; ++j) acc[i][j] = (f32x4){0.f, 0.f, 0.f, 0.f};

    for (int k0 = 0; k0 < K; k0 += 32) {
        __syncthreads();
        gl_lds16(gb0 + k0, lb0);
        gl_lds16(gb1 + k0, lb1);
        float4 a0 = *(const float4*)(gaf0 + k0);
        float4 a1 = *(const float4*)(gaf0 + k0 + 4);
        float4 a2 = *(const float4*)(gaf1 + k0);
        float4 a3 = *(const float4*)(gaf1 + k0 + 4);
        *(bf16x8*)lwa0 = cvt2bf8(a0, a1);
        *(bf16x8*)lwa1 = cvt2bf8(a2, a3);
        __syncthreads();
        bf16x8 af[4], bfv[4];
#pragma unroll
        for (int i = 0; i < 4; ++i)
            af[i] = *(const bf16x8*)&As[(wr * 64 + i * 16 + l15) * 32 + quad * 8];
#pragma unroll
        for (int j = 0; j < 4; ++j)
            bfv[j] = *(const bf16x8*)&Bs[(wc * 64 + j * 16 + l15) * 32 + quad * 8];
#pragma unroll
        for (int i = 0; i < 4; ++i)
#pragma unroll
            for (int j = 0; j < 4; ++j)
                acc[i][j] = __builtin_amdgcn_mfma_f32_16x16x32_bf16(af[i], bfv[j], acc[i][j], 0, 0, 0);
    }

#pragma unroll
    for (int i = 0; i < 4; ++i) {
        const int rg = row0 + wr * 64 + i * 16 + quad * 4;  // rows rg..rg+3
#pragma unroll
        for (int j = 0; j < 4; ++j) {
            const int cg = col0 + wc * 64 + j * 16 + l15;
            const float bb = bias[cg];
            const int b = rg >> 11, n = rg & 2047;          // 4 consecutive n
            const int h = cg >> 6, hd = cg & 63;
            const int nc = n >> 6, ks = (n >> 5) & 1, qj = (n >> 3) & 3, j0 = n & 7;
            const int jt = hd >> 4, fl = hd & 15;
            bf16x4 v;
#pragma unroll
            for (int r = 0; r < 4; ++r) v[r] = (__bf16)(acc[i][j][r] + bb);
            *(bf16x4*)&V3[(size_t)(((h * 32 + nc) * 4 + b) * 4096) +
                          (jt * 2 + ks) * 512 + fl * 32 + qj * 8 + j0] = v;
        }
    }
}

// ---------------------------------------------------------------------------
// Stage-4 GEMM (m97 recipe, bf16 A): out = yb @ Wot^T + bo, fp32 out.
// ---------------------------------------------------------------------------
__global__ __launch_bounds__(256) void gemm_bt(const __bf16* __restrict__ A,
                                               const __bf16* __restrict__ Bt,
                                               const float* __restrict__ bias,
                                               float* __restrict__ Cf,
                                               int M, int N, int K) {
    __shared__ alignas(16) __bf16 As[128 * 32];
    __shared__ alignas(16) __bf16 Bs[128 * 32];
    const int tid = threadIdx.x;
    const int lane = tid & 63;
    const int wid = __builtin_amdgcn_readfirstlane(tid >> 6);
    const int row0 = blockIdx.y * 128, col0 = blockIdx.x * 128;
    const int l15 = lane & 15, quad = lane >> 4;
    const int wr = wid & 1, wc = wid >> 1;
    const int s0 = wid * 2, s1 = s0 + 1;

    const __bf16* ga0 = A + (size_t)(row0 + s0 * 16 + (lane >> 2)) * K + ((lane & 3) << 3);
    const __bf16* ga1 = ga0 + (size_t)16 * K;
    const __bf16* gb0 = Bt + (size_t)(col0 + s0 * 16 + (lane >> 2)) * K + ((lane & 3) << 3);
    const __bf16* gb1 = gb0 + (size_t)16 * K;
    __bf16* la0 = As + s0 * 512;
    __bf16* la1 = As + s1 * 512;
    __bf16* lb0 = Bs + s0 * 512;
    __bf16* lb1 = Bs + s1 * 512;

    f32x4 acc[4][4];
#pragma unroll
    for (int i = 0; i < 4; ++i)
#pragma unroll
        for (int j = 0; j < 4; ++j) acc[i][j] = (f32x4){0.f, 0.f, 0.f, 0.f};

    for (int k0 = 0; k0 < K; k0 += 32) {
        __syncthreads();
        gl_lds16(ga0 + k0, la0);
        gl_lds16(ga1 + k0, la1);
        gl_lds16(gb0 + k0, lb0);
        gl_lds16(gb1 + k0, lb1);
        __syncthreads();
        bf16x8 af[4], bfv[4];
#pragma unroll
        for (int i = 0; i < 4; ++i)
            af[i] = *(const bf16x8*)&As[(wr * 64 + i * 16 + l15) * 32 + quad * 8];
#pragma unroll
        for (int j = 0; j < 4; ++j)
            bfv[j] = *(const bf16x8*)&Bs[(wc * 64 + j * 16 + l15) * 32 + quad * 8];
#pragma unroll
        for (int i = 0; i < 4; ++i)
#pragma unroll
            for (int j = 0; j < 4; ++j)
                acc[i][j] = __builtin_amdgcn_mfma_f32_16x16x32_bf16(af[i], bfv[j], acc[i][j], 0, 0, 0);
    }

#pragma unroll
    for (int i = 0; i < 4; ++i) {
        const int rg = row0 + wr * 64 + i * 16 + quad * 4;
#pragma unroll
        for (int j = 0; j < 4; ++j) {
            const int cg = col0 + wc * 64 + j * 16 + l15;
            const float bb = bias[cg];
#pragma unroll
            for (int r = 0; r < 4; ++r)
                Cf[(size_t)(rg + r) * N + cg] = acc[i][j][r] + bb;
        }
    }
}

// ---------------------------------------------------------------------------
// attn v6: S^T scores from register frags; V/r2 direct-global (no cross-wave
// reuse); P crosses waves via double-buffered conflict-free LDS tile
// (rows padded to 40 elems = 80 B: bank-granule = (5*l15+quad) mod 8 ->
// 2-per-granule spread; 80 B keeps b128 16-B aligned). ONE barrier/chunk.
// 512 threads, 128 l-rows/block, grid 256 (1/CU). Wave w: b=w&3, lh=w>>2.
// Denominators via ones-MFMA (C-layout, no shuffle reduction needed).
// ---------------------------------------------------------------------------
__global__ __launch_bounds__(512) void attn_pv_v6(const __bf16* __restrict__ r1b,
                                                  const __bf16* __restrict__ r2t,
                                                  const __bf16* __restrict__ V3,
                                                  __bf16* __restrict__ yb) {
    __shared__ alignas(16) __bf16 Ps[4 * 5120];   // [buf][lh] planes of 5120, 40 KB
    const int tid = threadIdx.x;
    const int lane = tid & 63;
    const int w = __builtin_amdgcn_readfirstlane(tid >> 6);
    const int b = w & 3, lh = w >> 2;
    const int l15 = lane & 15, quad = lane >> 4;
    const int id = blockIdx.x;
    const int h = id & 15;             // id%8 == h%8 -> per-XCD head locality
    const int l0 = (id >> 4) << 7;

    // r1 B-frags for this wave's 64 l (fixed)
    bf16x8 bf1[4];
#pragma unroll
    for (int i = 0; i < 4; ++i)
        bf1[i] = *(const bf16x8*)&r1b[(size_t)(h * 2048 + l0 + lh * 64 + i * 16 + l15) * 32 + quad * 8];

    const __bf16* r2p = r2t + (size_t)(h * 2048 + b * 16 + l15) * 32 + quad * 8;
    const __bf16* vp = V3 + (size_t)((h * 32) * 4 + b) * 4096 + l15 * 32 + quad * 8;

    // chunk-0 prefetch
    bf16x8 r2f = *(const bf16x8*)r2p;
    bf16x8 vpf[4][2];
#pragma unroll
    for (int jt = 0; jt < 4; ++jt)
#pragma unroll
        for (int ks = 0; ks < 2; ++ks)
            vpf[jt][ks] = *(const bf16x8*)(vp + (jt * 2 + ks) * 512);

    bf16x8 ones;
#pragma unroll
    for (int e = 0; e < 8; ++e) ones[e] = (__bf16)1.0f;

    f32x4 acc[4][4];
    f32x4 den[4];
#pragma unroll
    for (int i = 0; i < 4; ++i) {
        den[i] = (f32x4){0.f, 0.f, 0.f, 0.f};
#pragma unroll
        for (int j = 0; j < 4; ++j) acc[i][j] = (f32x4){0.f, 0.f, 0.f, 0.f};
    }
    const f32x4 zero4 = {0.f, 0.f, 0.f, 0.f};

    const int kw = b >> 1;                       // which ks this wave produces
    const int jg = (b & 1) * 2 + (quad >> 1);    // k-granule within ks segment
    const int q4 = (quad & 1) * 4;

    for (int c = 0; c < 32; ++c) {
        const int cn = (c < 31) ? 1 : 0;         // last chunk: re-load (harmless)
        const int nx = (c + 1) & 31;             // next chunk index (absolute)
        // scores S^T: rows = this wave's 16-n strip, cols = its 64 l
        f32x4 s[4];
#pragma unroll
        for (int i = 0; i < 4; ++i)
            s[i] = __builtin_amdgcn_mfma_f32_16x16x32_bf16(r2f, bf1[i], zero4, 0, 0, 0);
        r2f = *(const bf16x8*)(r2p + (size_t)nx * 2048);   // absolute chunk addr
        __bf16* ps = &Ps[((c & 1) * 2 + lh) * 5120];
#pragma unroll
        for (int i = 0; i < 4; ++i) {
            bf16x4 p4;
#pragma unroll
            for (int r = 0; r < 4; ++r) p4[r] = (__bf16)__expf(s[i][r]);
            *(bf16x4*)&ps[((i * 2 + kw) * 16 + l15) * 40 + jg * 8 + q4] = p4;
        }
        __syncthreads();
        bf16x8 pa[4][2];
#pragma unroll
        for (int i = 0; i < 4; ++i)
#pragma unroll
            for (int ks = 0; ks < 2; ++ks)
                pa[i][ks] = *(const bf16x8*)&ps[((i * 2 + ks) * 16 + l15) * 40 + quad * 8];
        // PV + denominators (consume vpf), then prefetch next chunk's V
#pragma unroll
        for (int ks = 0; ks < 2; ++ks) {
#pragma unroll
            for (int i = 0; i < 4; ++i) {
#pragma unroll
                for (int jt = 0; jt < 4; ++jt)
                    acc[i][jt] = __builtin_amdgcn_mfma_f32_16x16x32_bf16(pa[i][ks], vpf[jt][ks],
                                                                         acc[i][jt], 0, 0, 0);
                den[i] = __builtin_amdgcn_mfma_f32_16x16x32_bf16(pa[i][ks], ones, den[i], 0, 0, 0);
            }
        }
        vp += cn * 16384;
#pragma unroll
        for (int jt = 0; jt < 4; ++jt)
#pragma unroll
            for (int ks = 0; ks < 2; ++ks)
                vpf[jt][ks] = *(const bf16x8*)(vp + (jt * 2 + ks) * 512);
    }

    // epilogue: den[i][r] is the softmax denom for l = lh*64+i*16+quad*4+r (per-lane)
#pragma unroll
    for (int i = 0; i < 4; ++i) {
#pragma unroll
        for (int r = 0; r < 4; ++r) {
            const float iv = 1.0f / den[i][r];
            const int l = l0 + lh * 64 + i * 16 + quad * 4 + r;
            const size_t rowbase = ((size_t)b * LL + l) * 1024 + h * 64;
#pragma unroll
            for (int jt = 0; jt < 4; ++jt)
                yb[rowbase + jt * 16 + l15] = (__bf16)(acc[i][jt][r] * iv);
        }
    }
}

extern "C" void kernel_launch(void* const* d_in, const int* in_sizes, int n_in,
                              void* d_out, int out_size, void* d_ws, size_t ws_size,
                              hipStream_t stream) {
    const float* inputs_kv = (const float*)d_in[1];
    const float* Wv = (const float*)d_in[2];   // (D, H*HD)
    const float* bv = (const float*)d_in[3];   // (H*HD)
    const float* r1 = (const float*)d_in[4];   // (H, L, K)
    const float* r2 = (const float*)d_in[5];   // (H, K, L)
    const float* Wo = (const float*)d_in[6];   // (H*HD, D)
    const float* bo = (const float*)d_in[7];   // (D)
    float* out = (float*)d_out;

    char* ws = (char*)d_ws;
    const size_t MB = 1024 * 1024;
    __bf16* Wvt = (__bf16*)(ws);             //  2 MB  Wv^T
    __bf16* Wot = (__bf16*)(ws + 2 * MB);    //  2 MB  Wo^T
    __bf16* r1b = (__bf16*)(ws + 4 * MB);    //  2 MB  bf16(r1) [h][l][32]
    __bf16* r2t = (__bf16*)(ws + 6 * MB);    //  2 MB  r2^T per head [h][n][32]
    __bf16* V3  = (__bf16*)(ws + 8 * MB);    // 16 MB  V fragment-major
    __bf16* yb  = (__bf16*)(ws + 24 * MB);   // 16 MB  y [b][l][h*64+hd]

    prep<<<2048, 256, 0, stream>>>(r1, Wv, Wo, r2, r1b, Wvt, Wot, r2t);
    gemm_af32<<<dim3(8, 64), 256, 0, stream>>>(inputs_kv, Wvt, bv, V3, 8192, 1024, 1024);
    attn_pv_v6<<<256, 512, 0, stream>>>(r1b, r2t, V3, yb);
    gemm_bt<<<dim3(8, 64), 256, 0, stream>>>(yb, Wot, bo, out, 8192, 1024, 1024);
}